// Round 19
// baseline (54.486 us; speedup 1.0000x reference)
//
#include <hip/hip_runtime.h>
#include <hip/hip_bf16.h>

// Depth-4 path signature, C=10, L=64, B=2048 — MFMA formulation (R19).
// Closed form (validated R8-R18, absmax 5.25 vs thr 12.16):
//   P_t = exclusive prefix of dx;  R_t[l] = S1[l] - P_{t+1}[l]
//   per (i,j): s2 serial chain; u2_t, v2_t level-2 scalars
//   S4[ij,kl] = sum_t v2_t*(dx_t[k]*R_t[l]) + sum_t u2_t*(dx_t[k]*dx_t[l]/2)
//   S3[ij,k]  = sum_t v2_t*dx_t[k]
// Per-elem structure = R17 (best, 38.5us): two K=64 GEMM passes, U2 carried
// bf16-packed in VGPRs, v_cvt_pk_bf16_f32 packing, swapped-operand
// (transposed-C) GEMM, per-lane contiguous f2 epilogue.
// R19 delta (ONE structural change): 2 elems per 512-thread block.
// Waves 0-3 -> elem 0, waves 4-7 -> elem 1, disjoint 32.5KB LDS halves,
// shared (phase-aligned) barriers. __launch_bounds__(512,2): 2 blocks/CU
// = 16 waves/CU (50% ceiling, vs R17's 36%) with VGPR budget 128/wave —
// R18 proved (256,5) squeezes VGPR to 48 and spills acc to scratch
// (233MB writes); (512,2) raises waves WITHOUT touching the VGPR budget.

typedef short short8 __attribute__((ext_vector_type(8)));
typedef float f2 __attribute__((ext_vector_type(2)));
typedef float f32x4 __attribute__((ext_vector_type(4)));
typedef unsigned int uint4v __attribute__((ext_vector_type(4)));

constexpr int C = 10, L = 64, T = 63;          // T = L-1 steps
constexpr int OUTSZ = 10 + 100 + 1000 + 10000; // 11110
constexpr int DXP = 11;                        // dx/P row stride (fp32 words, odd)
constexpr int KS = 64;                         // per-pass row stride in shorts (128B)
constexpr int HALF_BYTES = 32480;              // per-elem LDS carve

__device__ __forceinline__ unsigned packbf(float lo, float hi) {  // v_cvt_pk_bf16_f32
  union { __hip_bfloat162 h; unsigned u; } cv;
  cv.h = __float22bfloat162_rn(make_float2(lo, hi));
  return cv.u;
}
__device__ __forceinline__ int swz(int row, int k) {  // short idx, 16B-granule XOR
  return row * KS + ((((k >> 3) ^ (row & 7)) << 3) | (k & 7));
}

__global__ __launch_bounds__(512, 2) void sig4_kernel(
    const float* __restrict__ x, float* __restrict__ out)
{
  __shared__ __align__(16) unsigned char smem_raw[2 * HALF_BYTES];  // 64960B

  const int t = threadIdx.x;
  const int e  = t >> 8;       // elem half (0/1)
  const int tl = t & 255;      // local tid within half

  unsigned char* base = smem_raw + e * HALF_BYTES;
  unsigned short* Ab = (unsigned short*)base;            // 100*64 sh = 12800B
  unsigned short* Bb = (unsigned short*)(base + 12800);  // 110*64 sh = 14080B
  float* dxs = (float*)(base + 26880);                   // 63*11 f = 2772B
  float* Ps  = (float*)(base + 29652);                   // 64*11 f = 2816B

  const float* __restrict__ xb = x + ((size_t)blockIdx.x * 2 + e) * (C * L);
  float* __restrict__ ob = out + ((size_t)blockIdx.x * 2 + e) * OUTSZ;

  // ---- phase A: path -> dx, exclusive prefix P (shuffle scan) ----
  float* pl = (float*)Bb;  // alias: Bb first written in build (after last pl read)
  for (int i = tl; i < C * L; i += 256) pl[i] = xb[i];
  __syncthreads();
  for (int i = tl; i < T * C; i += 256) {
    int s = i / C, c = i - s * C;
    dxs[s * DXP + c] = pl[c * L + s + 1] - pl[c * L + s];
  }
  __syncthreads();
  {
    int w0 = tl >> 6, lane0 = tl & 63;
    for (int c = w0; c < C; c += 4) {
      float v = (lane0 > 0) ? dxs[(lane0 - 1) * DXP + c] : 0.f;
      #pragma unroll
      for (int d = 1; d < 64; d <<= 1) {
        float y = __shfl_up(v, d);
        if (lane0 >= d) v += y;
      }
      Ps[lane0 * DXP + c] = v;  // P[t][c] = sum_{s<t} dx_s[c]; P[63] = S1
    }
  }
  __syncthreads();

  unsigned u2r[32];  // U2 bf16-packed (64 slots; slot 63 zero), static-indexed

  // ---- build pass 0: A=V2 (tl 0..99) || B=[dx ox R | dx] (tl 128..255) ----
  if (tl < 100) {
    const int i_ = tl / 10, j_ = tl - (tl / 10) * 10;
    float s2 = 0.f;
    #pragma unroll
    for (int ch = 0; ch < 8; ++ch) {
      float bu[8], bv[8], zz[8];
      #pragma unroll
      for (int ee = 0; ee < 8; ++ee) {   // pointwise, ILP-friendly
        const int s = ch * 8 + ee;
        if (s < T) {
          float di = dxs[s * DXP + i_];
          float dj = dxs[s * DXP + j_];
          float p  = Ps[s * DXP + i_];
          bu[ee] = fmaf(di, 0.25f, p) * (dj * (1.f / 3.f));
          bv[ee] = fmaf(di, (1.f / 3.f), p) * (dj * 0.5f);
          zz[ee] = fmaf(di, 0.5f, p) * dj;
        } else { bu[ee] = 0.f; bv[ee] = 0.f; zz[ee] = 0.f; }
      }
      float u2v[8], v2v[8];
      #pragma unroll
      for (int ee = 0; ee < 8; ++ee) {   // serial part: 1 dependent add/step
        u2v[ee] = bu[ee] + s2;
        v2v[ee] = bv[ee] + s2;
        s2 += zz[ee];
      }
      uint4v vp;
      #pragma unroll
      for (int q = 0; q < 4; ++q) {
        vp[q] = packbf(v2v[2 * q], v2v[2 * q + 1]);
        u2r[ch * 4 + q] = packbf(u2v[2 * q], u2v[2 * q + 1]);
      }
      *(uint4v*)&Ab[swz(tl, ch * 8)] = vp;
    }
    ob[10 + tl] = s2;                           // S2 (fp32)
    if (j_ == 0) ob[i_] = Ps[63 * DXP + i_];    // S1
  } else if (tl >= 128) {
    const int q = tl - 128;
    for (int task = q; task < 110 * 8; task += 128) {
      const int col = task >> 3, ch = task & 7;
      float b1v[8];
      if (col < 100) {
        const int k2 = col / 10, l2 = col - (col / 10) * 10;
        const float S1l = Ps[63 * DXP + l2];
        #pragma unroll
        for (int ee = 0; ee < 8; ++ee) {
          const int kk = ch * 8 + ee;
          b1v[ee] = (kk < T)
              ? dxs[kk * DXP + k2] * (S1l - Ps[(kk + 1) * DXP + l2]) : 0.f;
        }
      } else {
        const int c2 = col - 100;
        #pragma unroll
        for (int ee = 0; ee < 8; ++ee) {
          const int kk = ch * 8 + ee;
          b1v[ee] = (kk < T) ? dxs[kk * DXP + c2] : 0.f;
        }
      }
      uint4v pk;
      #pragma unroll
      for (int qq = 0; qq < 4; ++qq) pk[qq] = packbf(b1v[2 * qq], b1v[2 * qq + 1]);
      *(uint4v*)&Bb[swz(col, ch * 8)] = pk;
    }
  }
  __syncthreads();

  const int w = tl >> 6, lane = tl & 63;
  const int lm = lane & 15, lg = lane >> 4;

  f32x4 acc[2][7];
  #pragma unroll
  for (int rti = 0; rti < 2; ++rti)
    #pragma unroll
    for (int ct = 0; ct < 7; ++ct) acc[rti][ct] = f32x4{0.f, 0.f, 0.f, 0.f};

  // ---- GEMM, operands swapped -> transposed C (B reused across rt strips) ----
  #define GEMM_PASS()                                                          \
    do {                                                                       \
      short8 afr[2][2];                                                        \
      _Pragma("unroll")                                                        \
      for (int rti = 0; rti < 2; ++rti) {                                      \
        const int rt = w + rti * 4;                                            \
        const int arow = rt * 16 + lm;                                         \
        _Pragma("unroll")                                                      \
        for (int ks = 0; ks < 2; ++ks)                                         \
          afr[rti][ks] = (rt < 7 && arow < 100)                                \
              ? *(const short8*)&Ab[swz(arow, ks * 32 + lg * 8)]               \
              : short8{0, 0, 0, 0, 0, 0, 0, 0};                                \
      }                                                                        \
      for (int ct = 0; ct < 7; ++ct) {                                         \
        const int bcol = ct * 16 + lm;                                         \
        short8 b0 = (bcol < 110) ? *(const short8*)&Bb[swz(bcol, lg * 8)]      \
                                 : short8{0, 0, 0, 0, 0, 0, 0, 0};             \
        short8 b1 = (bcol < 110) ? *(const short8*)&Bb[swz(bcol, 32 + lg * 8)] \
                                 : short8{0, 0, 0, 0, 0, 0, 0, 0};             \
        _Pragma("unroll")                                                      \
        for (int rti = 0; rti < 2; ++rti) {                                    \
          if (w + rti * 4 < 7) {                                               \
            acc[rti][ct] = __builtin_amdgcn_mfma_f32_16x16x32_bf16(            \
                b0, afr[rti][0], acc[rti][ct], 0, 0, 0);                       \
            acc[rti][ct] = __builtin_amdgcn_mfma_f32_16x16x32_bf16(            \
                b1, afr[rti][1], acc[rti][ct], 0, 0, 0);                       \
          }                                                                    \
        }                                                                      \
      }                                                                        \
    } while (0)

  GEMM_PASS();   // pass 0: V2 x [dx ox R | dx]
  __syncthreads();

  // ---- build pass 1: A=U2 from registers || B=[dx ox dx /2 | 0] ----
  if (tl < 100) {
    #pragma unroll
    for (int ch = 0; ch < 8; ++ch)
      *(uint4v*)&Ab[swz(tl, ch * 8)] = uint4v{u2r[ch * 4], u2r[ch * 4 + 1],
                                              u2r[ch * 4 + 2], u2r[ch * 4 + 3]};
  } else if (tl >= 128) {
    const int q = tl - 128;
    for (int task = q; task < 110 * 8; task += 128) {
      const int col = task >> 3, ch = task & 7;
      float b2v[8] = {0.f, 0.f, 0.f, 0.f, 0.f, 0.f, 0.f, 0.f};
      if (col < 100) {
        const int k2 = col / 10, l2 = col - (col / 10) * 10;
        #pragma unroll
        for (int ee = 0; ee < 8; ++ee) {
          const int kk = ch * 8 + ee;
          b2v[ee] = (kk < T) ? dxs[kk * DXP + k2] * dxs[kk * DXP + l2] * 0.5f : 0.f;
        }
      }
      uint4v pk;
      #pragma unroll
      for (int qq = 0; qq < 4; ++qq) pk[qq] = packbf(b2v[2 * qq], b2v[2 * qq + 1]);
      *(uint4v*)&Bb[swz(col, ch * 8)] = pk;
    }
  }
  __syncthreads();

  GEMM_PASS();   // pass 1: U2 x [dx ox dx /2 | 0], accumulates

  // ---- epilogue: transposed acc -> per-lane contiguous f2 stores ----
  #pragma unroll
  for (int rti = 0; rti < 2; ++rti) {
    const int rt = w + rti * 4;
    if (rt < 7) {
      const int row = rt * 16 + lm;        // output ij-row
      if (row < 100) {
        float* rowp4 = ob + 1110 + row * 100;
        float* rowp3 = ob + 110 + row * 10;
        #pragma unroll
        for (int ct = 0; ct < 7; ++ct) {
          const int colbase = ct * 16 + lg * 4;   // output col (4 consecutive)
          f2 lo = {acc[rti][ct][0], acc[rti][ct][1]};
          f2 hi = {acc[rti][ct][2], acc[rti][ct][3]};
          if (colbase < 100) {                    // colbase <= 96 -> +3 <= 99
            *(f2*)(rowp4 + colbase) = lo;
            *(f2*)(rowp4 + colbase + 2) = hi;
          } else if (colbase < 110) {             // 100 / 104 / 108 -> S3
            *(f2*)(rowp3 + (colbase - 100)) = lo;
            if (colbase < 108) *(f2*)(rowp3 + (colbase - 98)) = hi;
          }
        }
      }
    }
  }
}

extern "C" void kernel_launch(void* const* d_in, const int* in_sizes, int n_in,
                              void* d_out, int out_size, void* d_ws, size_t ws_size,
                              hipStream_t stream) {
  const float* x = (const float*)d_in[0];
  float* out = (float*)d_out;
  const int batch = in_sizes[0] / (C * L);   // 2048
  sig4_kernel<<<dim3(batch / 2), dim3(512), 0, stream>>>(x, out);
}

// Round 20
// 35.928 us; speedup vs baseline: 1.5165x; 1.5165x over previous
//
#include <hip/hip_runtime.h>
#include <hip/hip_bf16.h>

// Depth-4 path signature, C=10, L=64, B=2048 — MFMA formulation (R20).
// Closed form (validated R8-R19, absmax 5.25 vs thr 12.16):
//   P_t = exclusive prefix of dx;  R_t[l] = S1[l] - P_{t+1}[l]
//   per (i,j): s2 serial chain; u2_t, v2_t level-2 scalars
//   S4[ij,kl] = sum_t v2_t*(dx_t[k]*R_t[l]) + sum_t u2_t*(dx_t[k]*dx_t[l]/2)
//   S3[ij,k]  = sum_t v2_t*dx_t[k]
// R20 vs R17 (best, 38.5us): widen WAVES not blocks (R18 VGPR-wall,
// R19 LDS-wall falsified the block axis). 512 thr / 1 elem / 8 waves:
//  - each GEMM wave owns ONE 16-row strip -> acc 28 VGPR (was 56);
//  - U2 written to LDS buffer Ub during the single build chain -> no
//    Ab-rewrite phase; pass-1 GEMM reads Ub;
//  - B0-build on 384 lanes (2.3 iters), B1-build on 512 (1.7 iters);
//  - dx from direct global reads (xb L2-resident) -> no pl staging;
//  - 5 barriers (was 7). LDS 45.3KB -> 3 blocks/CU = 24 waves/CU
//    with __launch_bounds__(512,6) (VGPR budget 85 >= ~80 needed).

typedef short short8 __attribute__((ext_vector_type(8)));
typedef float f2 __attribute__((ext_vector_type(2)));
typedef float f32x4 __attribute__((ext_vector_type(4)));
typedef unsigned int uint4v __attribute__((ext_vector_type(4)));

constexpr int C = 10, L = 64, T = 63;          // T = L-1 steps
constexpr int OUTSZ = 10 + 100 + 1000 + 10000; // 11110
constexpr int DXP = 11;                        // dx/P row stride (fp32 words, odd)
constexpr int KS = 64;                         // per-pass row stride in shorts (128B)

__device__ __forceinline__ unsigned packbf(float lo, float hi) {  // v_cvt_pk_bf16_f32
  union { __hip_bfloat162 h; unsigned u; } cv;
  cv.h = __float22bfloat162_rn(make_float2(lo, hi));
  return cv.u;
}
__device__ __forceinline__ int swz(int row, int k) {  // short idx, 16B-granule XOR
  return row * KS + ((((k >> 3) ^ (row & 7)) << 3) | (k & 7));
}

__global__ __launch_bounds__(512, 6) void sig4_kernel(
    const float* __restrict__ x, float* __restrict__ out)
{
  __shared__ __align__(16) unsigned char smem_raw[45280];
  unsigned short* Ab = (unsigned short*)smem_raw;            // V2: 100*64 sh = 12800B
  unsigned short* Ub = (unsigned short*)(smem_raw + 12800);  // U2: 100*64 sh = 12800B
  unsigned short* Bb = (unsigned short*)(smem_raw + 25600);  // 110*64 sh = 14080B
  float* dxs = (float*)(smem_raw + 39680);                   // 63*11 f = 2772B
  float* Ps  = (float*)(smem_raw + 42452);                   // 64*11 f = 2816B

  const int t = threadIdx.x;
  const int w = t >> 6, lane = t & 63;
  const float* __restrict__ xb = x + (size_t)blockIdx.x * (C * L);
  float* __restrict__ ob = out + (size_t)blockIdx.x * OUTSZ;

  // ---- phase A: dx direct from global (xb is 2.5KB, L1/L2-resident) ----
  for (int i = t; i < T * C; i += 512) {
    int c = i / T, s = i - c * T;            // consecutive lanes -> consecutive s
    dxs[s * DXP + c] = xb[c * L + s + 1] - xb[c * L + s];
  }
  __syncthreads();
  // exclusive prefix P over t (shuffle scan), one channel per wave
  for (int c = w; c < C; c += 8) {
    float v = (lane > 0) ? dxs[(lane - 1) * DXP + c] : 0.f;
    #pragma unroll
    for (int d = 1; d < 64; d <<= 1) {
      float y = __shfl_up(v, d);
      if (lane >= d) v += y;
    }
    Ps[lane * DXP + c] = v;   // P[t][c] = sum_{s<t} dx_s[c]; P[63] = S1
  }
  __syncthreads();

  // ---- build: A-chain (t<100) -> Ab(V2) + Ub(U2) || B0-build (t>=128) ----
  if (t < 100) {
    const int i_ = t / 10, j_ = t - (t / 10) * 10;
    float s2 = 0.f;
    #pragma unroll
    for (int ch = 0; ch < 8; ++ch) {
      float bu[8], bv[8], zz[8];
      #pragma unroll
      for (int ee = 0; ee < 8; ++ee) {       // pointwise, ILP-friendly
        const int s = ch * 8 + ee;
        if (s < T) {
          float di = dxs[s * DXP + i_];
          float dj = dxs[s * DXP + j_];
          float p  = Ps[s * DXP + i_];
          bu[ee] = fmaf(di, 0.25f, p) * (dj * (1.f / 3.f));
          bv[ee] = fmaf(di, (1.f / 3.f), p) * (dj * 0.5f);
          zz[ee] = fmaf(di, 0.5f, p) * dj;
        } else { bu[ee] = 0.f; bv[ee] = 0.f; zz[ee] = 0.f; }
      }
      float u2v[8], v2v[8];
      #pragma unroll
      for (int ee = 0; ee < 8; ++ee) {       // serial part: 1 dependent add/step
        u2v[ee] = bu[ee] + s2;
        v2v[ee] = bv[ee] + s2;
        s2 += zz[ee];
      }
      uint4v vp, up;
      #pragma unroll
      for (int q = 0; q < 4; ++q) {
        vp[q] = packbf(v2v[2 * q], v2v[2 * q + 1]);
        up[q] = packbf(u2v[2 * q], u2v[2 * q + 1]);
      }
      *(uint4v*)&Ab[swz(t, ch * 8)] = vp;
      *(uint4v*)&Ub[swz(t, ch * 8)] = up;
    }
    ob[10 + t] = s2;                            // S2 (fp32)
    if (j_ == 0) ob[i_] = Ps[63 * DXP + i_];    // S1
  } else if (t >= 128) {
    const int q = t - 128;                      // 384 lanes
    for (int task = q; task < 110 * 8; task += 384) {
      const int col = task >> 3, ch = task & 7;
      float b1v[8];
      if (col < 100) {
        const int k2 = col / 10, l2 = col - (col / 10) * 10;
        const float S1l = Ps[63 * DXP + l2];
        #pragma unroll
        for (int ee = 0; ee < 8; ++ee) {
          const int kk = ch * 8 + ee;
          b1v[ee] = (kk < T)
              ? dxs[kk * DXP + k2] * (S1l - Ps[(kk + 1) * DXP + l2]) : 0.f;
        }
      } else {
        const int c2 = col - 100;
        #pragma unroll
        for (int ee = 0; ee < 8; ++ee) {
          const int kk = ch * 8 + ee;
          b1v[ee] = (kk < T) ? dxs[kk * DXP + c2] : 0.f;
        }
      }
      uint4v pk;
      #pragma unroll
      for (int qq = 0; qq < 4; ++qq) pk[qq] = packbf(b1v[2 * qq], b1v[2 * qq + 1]);
      *(uint4v*)&Bb[swz(col, ch * 8)] = pk;
    }
  }
  __syncthreads();

  const int lm = lane & 15, lg = lane >> 4;
  f32x4 acc[7];
  #pragma unroll
  for (int ct = 0; ct < 7; ++ct) acc[ct] = f32x4{0.f, 0.f, 0.f, 0.f};

  // ---- GEMM pass 0: one rt-strip per wave (waves 0..6), A=V2 ----
  if (w < 7) {
    const int arow = w * 16 + lm;
    short8 a0 = (arow < 100) ? *(const short8*)&Ab[swz(arow, lg * 8)]
                             : short8{0, 0, 0, 0, 0, 0, 0, 0};
    short8 a1 = (arow < 100) ? *(const short8*)&Ab[swz(arow, 32 + lg * 8)]
                             : short8{0, 0, 0, 0, 0, 0, 0, 0};
    #pragma unroll
    for (int ct = 0; ct < 7; ++ct) {
      const int bcol = ct * 16 + lm;
      short8 b0 = (bcol < 110) ? *(const short8*)&Bb[swz(bcol, lg * 8)]
                               : short8{0, 0, 0, 0, 0, 0, 0, 0};
      short8 b1 = (bcol < 110) ? *(const short8*)&Bb[swz(bcol, 32 + lg * 8)]
                               : short8{0, 0, 0, 0, 0, 0, 0, 0};
      acc[ct] = __builtin_amdgcn_mfma_f32_16x16x32_bf16(b0, a0, acc[ct], 0, 0, 0);
      acc[ct] = __builtin_amdgcn_mfma_f32_16x16x32_bf16(b1, a1, acc[ct], 0, 0, 0);
    }
  }
  __syncthreads();

  // ---- build B1 = [dx ox dx /2 | 0] on ALL 512 lanes ----
  for (int task = t; task < 110 * 8; task += 512) {
    const int col = task >> 3, ch = task & 7;
    float b2v[8] = {0.f, 0.f, 0.f, 0.f, 0.f, 0.f, 0.f, 0.f};
    if (col < 100) {
      const int k2 = col / 10, l2 = col - (col / 10) * 10;
      #pragma unroll
      for (int ee = 0; ee < 8; ++ee) {
        const int kk = ch * 8 + ee;
        b2v[ee] = (kk < T) ? dxs[kk * DXP + k2] * dxs[kk * DXP + l2] * 0.5f : 0.f;
      }
    }
    uint4v pk;
    #pragma unroll
    for (int qq = 0; qq < 4; ++qq) pk[qq] = packbf(b2v[2 * qq], b2v[2 * qq + 1]);
    *(uint4v*)&Bb[swz(col, ch * 8)] = pk;
  }
  __syncthreads();

  // ---- GEMM pass 1: A=U2 (from Ub), accumulates ----
  if (w < 7) {
    const int arow = w * 16 + lm;
    short8 a0 = (arow < 100) ? *(const short8*)&Ub[swz(arow, lg * 8)]
                             : short8{0, 0, 0, 0, 0, 0, 0, 0};
    short8 a1 = (arow < 100) ? *(const short8*)&Ub[swz(arow, 32 + lg * 8)]
                             : short8{0, 0, 0, 0, 0, 0, 0, 0};
    #pragma unroll
    for (int ct = 0; ct < 7; ++ct) {
      const int bcol = ct * 16 + lm;
      short8 b0 = (bcol < 110) ? *(const short8*)&Bb[swz(bcol, lg * 8)]
                               : short8{0, 0, 0, 0, 0, 0, 0, 0};
      short8 b1 = (bcol < 110) ? *(const short8*)&Bb[swz(bcol, 32 + lg * 8)]
                               : short8{0, 0, 0, 0, 0, 0, 0, 0};
      acc[ct] = __builtin_amdgcn_mfma_f32_16x16x32_bf16(b0, a0, acc[ct], 0, 0, 0);
      acc[ct] = __builtin_amdgcn_mfma_f32_16x16x32_bf16(b1, a1, acc[ct], 0, 0, 0);
    }

    // ---- epilogue: transposed acc -> per-lane contiguous f2 stores ----
    const int row = w * 16 + lm;           // output ij-row
    if (row < 100) {
      float* rowp4 = ob + 1110 + row * 100;
      float* rowp3 = ob + 110 + row * 10;
      #pragma unroll
      for (int ct = 0; ct < 7; ++ct) {
        const int colbase = ct * 16 + lg * 4;   // 4 consecutive output cols
        f2 lo = {acc[ct][0], acc[ct][1]};
        f2 hi = {acc[ct][2], acc[ct][3]};
        if (colbase < 100) {                    // colbase <= 96 -> +3 <= 99
          *(f2*)(rowp4 + colbase) = lo;
          *(f2*)(rowp4 + colbase + 2) = hi;
        } else if (colbase < 110) {             // 100 / 104 / 108 -> S3
          *(f2*)(rowp3 + (colbase - 100)) = lo;
          if (colbase < 108) *(f2*)(rowp3 + (colbase - 98)) = hi;
        }
      }
    }
  }
}

extern "C" void kernel_launch(void* const* d_in, const int* in_sizes, int n_in,
                              void* d_out, int out_size, void* d_ws, size_t ws_size,
                              hipStream_t stream) {
  const float* x = (const float*)d_in[0];
  float* out = (float*)d_out;
  const int batch = in_sizes[0] / (C * L);   // 2048
  sig4_kernel<<<dim3(batch), dim3(512), 0, stream>>>(x, out);
}